// Round 3
// baseline (311.772 us; speedup 1.0000x reference)
//
#include <hip/hip_runtime.h>

// SSIM_13443247637111 — fused separable SSIM, round 3.
// LDS-instruction-count optimized: V-pass 2 rows/thread (12-row sweep),
// H-pass 16 outputs/thread (8-quad window), SUP=16 supers, 26-slot ring.
// Block = 256 thr, strip = 64 wide x 256 tall, grid 8x2x48 = 768 blocks.
// LDS = 58.5 KB -> 2 blocks/CU.

#define IMH 512
#define IMW 512
#define NCH 3
#define SW 64
#define SH 256
#define SUPR 16
#define NSUP (SH / SUPR)   // 16
#define DATQ 20            // data quads per staged row (80 cols, x in [-8,72))
#define PITCH 84           // row pitch in floats (21 quads, odd quad stride)
#define RS 26              // ring slots (16 + 10 halo)
#define NBLK 768

__device__ __forceinline__ float4 ld4(const float* p) { return *(const float4*)p; }
__device__ __forceinline__ void st4(float* p, float4 v) { *(float4*)p = v; }
__device__ __forceinline__ float4 mul4(float4 a, float4 b) {
    return make_float4(a.x*b.x, a.y*b.y, a.z*b.z, a.w*b.w);
}
__device__ __forceinline__ void fma4(float4& a, float w, float4 x) {
    a.x = fmaf(w, x.x, a.x); a.y = fmaf(w, x.y, a.y);
    a.z = fmaf(w, x.z, a.z); a.w = fmaf(w, x.w, a.w);
}
__device__ __forceinline__ void add4(float4& a, float4 x) {
    a.x += x.x; a.y += x.y; a.z += x.z; a.w += x.w;
}

__global__ __launch_bounds__(256, 2) void ssim_main(
    const float* __restrict__ img1, const float* __restrict__ img2,
    const float* __restrict__ match,
    float* __restrict__ wsn, float* __restrict__ wsd,
    double* __restrict__ acc, int use_partials)
{
    __shared__ __align__(16) float ring1[RS][PITCH];
    __shared__ __align__(16) float ring2[RS][PITCH];
    __shared__ __align__(16) float ringm[RS][PITCH];
    __shared__ __align__(16) float fld[6][SUPR][PITCH];
    __shared__ float redn[4], redd[4];

    const int tid = threadIdx.x;
    const int bc = blockIdx.z;
    const int b = bc / NCH;
    const int c = bc - b * NCH;
    const int ystart = blockIdx.y * SH;
    const int bx0 = blockIdx.x * SW - 8;     // global x of LDS col 0

    const float* p1 = img1 + (size_t)(b * NCH + c) * (IMH * IMW);
    const float* p2 = img2 + (size_t)(b * NCH + c) * (IMH * IMW);
    const float* pm = match + (size_t)b * (IMH * IMW);

    float g[11];
    {
        float s = 0.0f;
        #pragma unroll
        for (int i = 0; i < 11; ++i) {
            float d = (float)(i - 5);
            g[i] = expf(-(d * d) / 4.5f);
            s += g[i];
        }
        #pragma unroll
        for (int i = 0; i < 11; ++i) g[i] /= s;
    }

    float num = 0.0f, den = 0.0f;

    // stage nrows rows starting at gy0 into the ring (zero-padded)
    auto stage = [&](int gy0, int nrows) {
        for (int t = tid; t < nrows * DATQ; t += 256) {
            int r = t / DATQ, q = t - r * DATQ;
            int gy = gy0 + r;
            int slot = (gy + 520) % RS;      // 520 = 20*26
            int gx = bx0 + 4 * q;
            float4 v1, v2, vm;
            if ((unsigned)gy < IMH && gx >= 0 && gx <= (IMW - 4)) {
                int off = gy * IMW + gx;
                v1 = ld4(p1 + off);
                v2 = ld4(p2 + off);
                vm = ld4(pm + off);
            } else if ((unsigned)gy < IMH) {
                float t1[4], t2[4], tm[4];
                #pragma unroll
                for (int e = 0; e < 4; ++e) {
                    int x = gx + e;
                    bool ok = (unsigned)x < IMW;
                    int off = gy * IMW + (ok ? x : 0);
                    t1[e] = ok ? p1[off] : 0.0f;
                    t2[e] = ok ? p2[off] : 0.0f;
                    tm[e] = ok ? pm[off] : 0.0f;
                }
                v1 = make_float4(t1[0], t1[1], t1[2], t1[3]);
                v2 = make_float4(t2[0], t2[1], t2[2], t2[3]);
                vm = make_float4(tm[0], tm[1], tm[2], tm[3]);
            } else {
                v1 = v2 = vm = make_float4(0.f, 0.f, 0.f, 0.f);
            }
            st4(&ring1[slot][4 * q], v1);
            st4(&ring2[slot][4 * q], v2);
            st4(&ringm[slot][4 * q], vm);
        }
    };

    // prologue: raw rows ystart-5 .. ystart+4
    stage(ystart - 5, 10);

    for (int s = 0; s < NSUP; ++s) {
        const int ybase = ystart + s * SUPR;

        // stage the 16 new raw rows (ybase+5 .. ybase+20); overwrites slots
        // last read by V of super s-1 (done before B2 of s-1).
        stage(ybase + 5, SUPR);
        __syncthreads();   // B1

        // ---- vertical pass: 160 tasks, 2 output rows per thread ----
        if (tid < 160) {
            int q = tid % DATQ, pr = tid / DATQ;   // pr in 0..7
            int cq = 4 * q;
            int y0 = ybase + 2 * pr;
            int sv = (y0 - 5 + 520) % RS;
            float4 A0[6], A1[6];
            #pragma unroll
            for (int f = 0; f < 6; ++f) {
                A0[f] = make_float4(0.f, 0.f, 0.f, 0.f);
                A1[f] = make_float4(0.f, 0.f, 0.f, 0.f);
            }
            #pragma unroll
            for (int k = 0; k < 12; ++k) {
                int sr = sv + k; if (sr >= RS) sr -= RS;
                float4 x1 = ld4(&ring1[sr][cq]);
                float4 x2 = ld4(&ring2[sr][cq]);
                float4 xm = ld4(&ringm[sr][cq]);
                float4 p11 = mul4(x1, x1);
                float4 p22 = mul4(x2, x2);
                float4 p12 = mul4(x1, x2);
                if (k < 11) {
                    float w = g[k];
                    fma4(A0[0], w, x1);  fma4(A0[1], w, x2);
                    fma4(A0[2], w, p11); fma4(A0[3], w, p22);
                    fma4(A0[4], w, p12); add4(A0[5], xm);
                }
                if (k > 0) {
                    float w = g[k - 1];
                    fma4(A1[0], w, x1);  fma4(A1[1], w, x2);
                    fma4(A1[2], w, p11); fma4(A1[3], w, p22);
                    fma4(A1[4], w, p12); add4(A1[5], xm);
                }
            }
            int r0 = 2 * pr;
            #pragma unroll
            for (int f = 0; f < 6; ++f) {
                st4(&fld[f][r0][cq], A0[f]);
                st4(&fld[f][r0 + 1][cq], A1[f]);
            }
        }
        __syncthreads();   // B2

        // ---- horizontal pass + SSIM: 64 tasks, 16 outputs per thread ----
        if (tid < 64) {
            int r = tid >> 2, gc = tid & 3;
            int base = 16 * gc;                 // fld col of window start
            float W[32];
            auto loadW = [&](int f) {
                #pragma unroll
                for (int i = 0; i < 8; ++i) {
                    float4 v = ld4(&fld[f][r][base + 4 * i]);
                    W[4*i] = v.x; W[4*i+1] = v.y; W[4*i+2] = v.z; W[4*i+3] = v.w;
                }
            };
            auto convW = [&](float* out) {
                #pragma unroll
                for (int j = 0; j < 16; ++j) {
                    float a = 0.0f;
                    #pragma unroll
                    for (int k = 0; k < 11; ++k) a = fmaf(g[k], W[j + 3 + k], a);
                    out[j] = a;
                }
            };
            float mu1[16]; loadW(0); convW(mu1);
            float mu2[16]; loadW(1); convW(mu2);
            float S1[16];  loadW(2); convW(S1);
            #pragma unroll
            for (int j = 0; j < 16; ++j) S1[j] -= mu1[j] * mu1[j];
            float D2[16];  loadW(3); convW(D2);
            #pragma unroll
            for (int j = 0; j < 16; ++j)
                D2[j] = (D2[j] - mu2[j] * mu2[j]) + S1[j] + 9e-4f;
            float N2[16];  loadW(4); convW(N2);
            #pragma unroll
            for (int j = 0; j < 16; ++j)
                N2[j] = 2.0f * (N2[j] - mu1[j] * mu2[j]) + 9e-4f;
            float N1[16], D1[16];
            #pragma unroll
            for (int j = 0; j < 16; ++j) {
                N1[j] = 2.0f * mu1[j] * mu2[j] + 1e-4f;
                D1[j] = mu1[j] * mu1[j] + mu2[j] * mu2[j] + 1e-4f;
            }
            float MB[16];  loadW(5);
            #pragma unroll
            for (int j = 0; j < 16; ++j) {
                float a = 0.0f;
                #pragma unroll
                for (int k = 0; k < 11; ++k) a += W[j + 3 + k];
                MB[j] = a;
            }
            #pragma unroll
            for (int j = 0; j < 16; ++j) {
                float ssim = (N1[j] * N2[j]) / (D1[j] * D2[j]);
                float m = fmaf(MB[j], (1.0f / 121.0f), 1e-7f);
                float mask = (m > 0.5f) ? (1.0f + 1e-7f) : 1e-7f;
                num = fmaf(1.0f - ssim, mask, num);
                den += mask;
            }
        }
    }

    // ---- block reduction ----
    for (int off = 32; off > 0; off >>= 1) {
        num += __shfl_down(num, off);
        den += __shfl_down(den, off);
    }
    int wave = tid >> 6;
    int lane = tid & 63;
    if (lane == 0) { redn[wave] = num; redd[wave] = den; }
    __syncthreads();
    if (tid == 0) {
        float n = redn[0] + redn[1] + redn[2] + redn[3];
        float d = redd[0] + redd[1] + redd[2] + redd[3];
        if (use_partials) {
            int bid = (blockIdx.z * gridDim.y + blockIdx.y) * gridDim.x + blockIdx.x;
            wsn[bid] = n;
            wsd[bid] = d;
        } else {
            atomicAdd(&acc[0], (double)n);
            if (c == 0) atomicAdd(&acc[1], (double)d);
        }
    }
}

__global__ void finalize_partials(const float* __restrict__ wsn,
                                  const float* __restrict__ wsd,
                                  float* __restrict__ out) {
    __shared__ double rn[4], rd[4];
    int tid = threadIdx.x;
    double num = 0.0, den = 0.0;
    for (int i = tid; i < NBLK; i += 256) {
        num += (double)wsn[i];
        int z = i >> 4;            // grid 8x2 per z -> 16 blocks per z
        if (z % NCH == 0) den += (double)wsd[i];
    }
    for (int off = 32; off > 0; off >>= 1) {
        num += __shfl_down(num, off);
        den += __shfl_down(den, off);
    }
    int wave = tid >> 6, lane = tid & 63;
    if (lane == 0) { rn[wave] = num; rd[wave] = den; }
    __syncthreads();
    if (tid == 0) {
        num = rn[0] + rn[1] + rn[2] + rn[3];
        den = rd[0] + rd[1] + rd[2] + rd[3];
        out[0] = (float)(num / den / 3.0);
    }
}

__global__ void init_acc(double* acc) { acc[0] = 0.0; acc[1] = 0.0; }

__global__ void finalize_atomic(const double* __restrict__ acc,
                                float* __restrict__ out) {
    out[0] = (float)(acc[0] / acc[1] / 3.0);
}

extern "C" void kernel_launch(void* const* d_in, const int* in_sizes, int n_in,
                              void* d_out, int out_size, void* d_ws, size_t ws_size,
                              hipStream_t stream) {
    const float* img1  = (const float*)d_in[0];
    const float* img2  = (const float*)d_in[1];
    const float* match = (const float*)d_in[2];
    float* out = (float*)d_out;

    dim3 grid(IMW / SW, IMH / SH, 16 * NCH);   // 8 x 2 x 48 = 768
    dim3 block(256, 1, 1);

    int use_partials = (ws_size >= (size_t)(2 * NBLK * sizeof(float))) ? 1 : 0;
    if (use_partials) {
        float* wsn = (float*)d_ws;
        float* wsd = wsn + NBLK;
        ssim_main<<<grid, block, 0, stream>>>(img1, img2, match, wsn, wsd,
                                              (double*)nullptr, 1);
        finalize_partials<<<1, 256, 0, stream>>>(wsn, wsd, out);
    } else {
        double* acc = (double*)d_ws;
        init_acc<<<1, 1, 0, stream>>>(acc);
        ssim_main<<<grid, block, 0, stream>>>(img1, img2, match,
                                              (float*)nullptr, (float*)nullptr,
                                              acc, 0);
        finalize_atomic<<<1, 1, 0, stream>>>(acc, out);
    }
}